// Round 16
// baseline (163.970 us; speedup 1.0000x reference)
//
#include <hip/hip_runtime.h>

typedef unsigned short u16;
typedef __attribute__((ext_vector_type(4))) float f32x4;
typedef __attribute__((ext_vector_type(8))) _Float16 f16x8;
typedef __attribute__((ext_vector_type(8))) unsigned short u16x8;
typedef __attribute__((ext_vector_type(4))) unsigned short u16x4;

#define DEV __device__ __forceinline__

// ---------- helpers ----------
DEV u16 f2h(float f) {
    _Float16 h = (_Float16)f;
    u16 r;
    __builtin_memcpy(&r, &h, 2);
    return r;
}
DEV float h2f(u16 u) {
    _Float16 h;
    __builtin_memcpy(&h, &u, 2);
    return (float)h;
}

DEV f32x4 mfma16(f16x8 a, f16x8 b, f32x4 c) {
    return __builtin_amdgcn_mfma_f32_16x16x32_f16(a, b, c, 0, 0, 0);
}

DEV void gload16(const void* g, void* l) {
    __builtin_amdgcn_global_load_lds(
        (const __attribute__((address_space(1))) void*)g,
        (__attribute__((address_space(3))) void*)l, 16, 0, 0);
}

// ---- cross-lane reduce over lanes {l ^ 16, l ^ 32} (same l15, kg=0..3) ----
#if __has_builtin(__builtin_amdgcn_permlane16_swap) && __has_builtin(__builtin_amdgcn_permlane32_swap)
DEV float redmax4(float x) {
    unsigned u = __float_as_uint(x);
    auto a = __builtin_amdgcn_permlane16_swap(u, u, false, false);
    x = fmaxf(__uint_as_float(a[0]), __uint_as_float(a[1]));
    u = __float_as_uint(x);
    auto b = __builtin_amdgcn_permlane32_swap(u, u, false, false);
    return fmaxf(__uint_as_float(b[0]), __uint_as_float(b[1]));
}
DEV float redsum4(float x) {
    unsigned u = __float_as_uint(x);
    auto a = __builtin_amdgcn_permlane16_swap(u, u, false, false);
    x = __uint_as_float(a[0]) + __uint_as_float(a[1]);
    u = __float_as_uint(x);
    auto b = __builtin_amdgcn_permlane32_swap(u, u, false, false);
    return __uint_as_float(b[0]) + __uint_as_float(b[1]);
}
#else
DEV float redmax4(float x) {
    x = fmaxf(x, __shfl_xor(x, 16));
    return fmaxf(x, __shfl_xor(x, 32));
}
DEV float redsum4(float x) {
    x += __shfl_xor(x, 16);
    return x + __shfl_xor(x, 32);
}
#endif

// ---------- problem constants ----------
#define BB 4
#define NN 4096
#define CC 512
#define CI 256
#define RR (BB * NN)  // 16384

// ---------- workspace layout (bytes) ----------
#define OFF_FEAT 0u                     // 16 MB: attn partial O splits 0,1
#define OFF_Q    16777216u
#define OFF_K    25165824u
#define OFF_V    33554432u              // V^T layout [b][d][key], keys sigma-permuted per 32
#define OFF_Y    41943040u              // 8MB: bn partials (512KB) early; yb (8MB) later
#define OFF_WQKV 50331648u
#define OFF_WO   51118080u
#define OFF_BQKV 51380224u
#define OFF_PART 51383296u              // 512KB: attn m/l
#define OFF_SS   51907584u

// ============ BN stats ============
__global__ void bn_partial(const float* __restrict__ x, float* __restrict__ part) {
    const int c = threadIdx.x;
    const int blk = blockIdx.x;           // 128 blocks x 128 rows
    const float* xp = x + (size_t)blk * 128 * CC + c;
    float s = 0.f, q = 0.f;
    for (int r = 0; r < 128; r++) {
        float v = xp[(size_t)r * CC];
        s += v; q += v * v;
    }
    part[blk * 1024 + c] = s;
    part[blk * 1024 + 512 + c] = q;
}

// ============ merged: bn_final (block 1024) + weight cvt (blocks 0..1023) ============
__global__ void prep_kernel(const float* __restrict__ part,
                            const float* __restrict__ gamma, const float* __restrict__ beta,
                            float* __restrict__ ss,
                            const float* __restrict__ thw, const float* __restrict__ phw,
                            const float* __restrict__ gw,
                            const float* __restrict__ thb, const float* __restrict__ phb,
                            const float* __restrict__ gb,
                            const float* __restrict__ ww,
                            u16* __restrict__ wqkv, u16* __restrict__ wo,
                            float* __restrict__ bqkv) {
    if (blockIdx.x == 1024) {
        const int c = threadIdx.x;  // 512 threads
        float s = 0.f, q = 0.f;
        for (int i = 0; i < 128; i++) {
            s += part[i * 1024 + c];
            q += part[i * 1024 + 512 + c];
        }
        float m = s * (1.0f / (float)RR);
        float var = q * (1.0f / (float)RR) - m * m;
        float istd = rsqrtf(var + 1e-5f);
        float g = gamma[c] * istd;
        ss[c] = g;
        ss[512 + c] = beta[c] - m * g;
        return;
    }
    const int idx = blockIdx.x * 512 + threadIdx.x;  // 0..524287
    if (idx < 768 * 512) {
        int row = idx >> 9, col = idx & 511;
        float v = (row < 256) ? thw[row * 512 + col]
                : (row < 512) ? phw[(row - 256) * 512 + col]
                              : gw[(row - 512) * 512 + col];
        wqkv[idx] = f2h(v);
    } else {
        int j = idx - 768 * 512;  // < 512*256
        wo[j] = f2h(ww[j]);
    }
    if (idx < 768) {
        bqkv[idx] = (idx < 256) ? thb[idx] : (idx < 512) ? phb[idx - 256] : gb[idx - 512];
    }
}

// ============ GEMM, 128x256 tile, 8 waves (2m x 4n), per-wave 64x64 acc[4][4] ============
// MODE 0: A = BN+ReLU(x) on the fly; grid (128,3); Q,K row-major; V^T sigma-permuted
// MODE 1: A = yb fp16 (gload_lds); grid (128,2); out = x + A*B^T + bias -> fp32
template <int MODE>
__global__ __launch_bounds__(512) void gemm_bt(
    const u16* __restrict__ A, const float* __restrict__ X, const float* __restrict__ ss,
    const u16* __restrict__ Bm, int K,
    const float* __restrict__ bias, const float* __restrict__ xres,
    u16* __restrict__ oq, u16* __restrict__ okk, u16* __restrict__ ov,
    float* __restrict__ of) {
    __shared__ u16 As[128 * 32];
    __shared__ u16 Bs[256 * 32];
    const int tid = threadIdx.x;          // 0..511
    const int lane = tid & 63;
    const int l15 = lane & 15, kg = lane >> 4;
    const int wv = tid >> 6;              // 0..7
    const int wm = wv >> 2, wn = wv & 3;  // wave owns 64 rows x 64 cols
    const int m0 = blockIdx.x * 128, n0 = blockIdx.y * 256;

    f32x4 acc[4][4];
    #pragma unroll
    for (int i = 0; i < 4; i++)
        #pragma unroll
        for (int j = 0; j < 4; j++) acc[i][j] = (f32x4){0.f, 0.f, 0.f, 0.f};

    const int rowA = tid >> 2, colA = (tid & 3) * 8;   // 512 threads cover 128 rows x 32 cols
    for (int k0 = 0; k0 < K; k0 += 32) {
        if constexpr (MODE == 0) {
            // fused BN+ReLU A-staging from x (fp32), one row per thread
            const float* xa = X + (size_t)(m0 + rowA) * CC + k0 + colA;
            f32x4 xv0 = *(const f32x4*)(xa);
            f32x4 xv1 = *(const f32x4*)(xa + 4);
            f32x4 sc0 = *(const f32x4*)(ss + k0 + colA);
            f32x4 sc1 = *(const f32x4*)(ss + k0 + colA + 4);
            f32x4 sh0 = *(const f32x4*)(ss + 512 + k0 + colA);
            f32x4 sh1 = *(const f32x4*)(ss + 512 + k0 + colA + 4);
            u16x8 a0;
            #pragma unroll
            for (int e = 0; e < 4; e++) {
                a0[e]     = f2h(fmaxf(xv0[e] * sc0[e] + sh0[e], 0.f));
                a0[4 + e] = f2h(fmaxf(xv1[e] * sc1[e] + sh1[e], 0.f));
            }
            *(u16x8*)&As[tid * 8] = a0;
        } else {
            gload16(A + (size_t)(m0 + rowA) * K + k0 + colA, &As[tid * 8]);
        }
        // B: 256 rows x 32 cols; each thread stages 2 rows
        gload16(Bm + (size_t)(n0 + rowA) * K + k0 + colA, &Bs[tid * 8]);
        gload16(Bm + (size_t)(n0 + 128 + rowA) * K + k0 + colA, &Bs[4096 + tid * 8]);
        __syncthreads();
        f16x8 af[4], bfr[4];
        #pragma unroll
        for (int i = 0; i < 4; i++)
            af[i] = *(const f16x8*)&As[(wm * 64 + i * 16 + l15) * 32 + kg * 8];
        #pragma unroll
        for (int i = 0; i < 4; i++)
            bfr[i] = *(const f16x8*)&Bs[(wn * 64 + i * 16 + l15) * 32 + kg * 8];
        #pragma unroll
        for (int mi = 0; mi < 4; mi++)
            #pragma unroll
            for (int ni = 0; ni < 4; ni++)
                acc[mi][ni] = mfma16(af[mi], bfr[ni], acc[mi][ni]);
        __syncthreads();
    }

    #pragma unroll
    for (int mi = 0; mi < 4; mi++) {
        #pragma unroll
        for (int ni = 0; ni < 4; ni++) {
            #pragma unroll
            for (int r = 0; r < 4; r++) {
                int row = m0 + wm * 64 + mi * 16 + kg * 4 + r;
                int col = n0 + wn * 64 + ni * 16 + l15;
                float v = acc[mi][ni][r];
                if constexpr (MODE == 0) {
                    v += bias[col];
                    u16 hv = f2h(v);
                    if (col < 256) {
                        oq[(size_t)row * CI + col] = hv;
                    } else if (col < 512) {
                        okk[(size_t)row * CI + (col - 256)] = hv;
                    } else {
                        int d = col - 512;
                        int bi = row >> 12, key = row & (NN - 1);
                        int k5 = key & 31;
                        int skey = (key & ~31) |
                                   ((((k5 >> 2) & 3) << 3) | (k5 & 3) | (((k5 >> 4) & 1) << 2));
                        ov[((size_t)bi * CI + d) * NN + skey] = hv;  // V^T, sigma-permuted
                    }
                } else {
                    size_t o = (size_t)row * 512 + col;
                    of[o] = xres[o] + v + bias[col];
                }
            }
        }
    }
}

// ============ flash attention, swapped-QK^T, 32 q-rows/wave, split-KV x4 ============
// grid 512 = 4 batches x 32 q-tiles(128 rows) x 4 key-splits; block 256 = 4 waves x 32 q-rows
// LDS: Ks 2x[32][256] swz (32KB dbuf) | Vt 2x[256][32] swz (32KB dbuf) = 65536 B
#define KVB 32
#define NSPLIT 4
#define KEYS_PER (NN / NSPLIT)          // 1024
#define NTILE (KEYS_PER / KVB)          // 32
#define ATTN_LDS 65536

__global__ __launch_bounds__(256, 2) void attn_kernel(
    const u16* __restrict__ Qg, const u16* __restrict__ Kg,
    const u16* __restrict__ Vtg, u16* __restrict__ po01, u16* __restrict__ po23,
    float* __restrict__ ml) {
    extern __shared__ u16 smem[];

    const int tid = threadIdx.x, lane = tid & 63, wv = tid >> 6;
    const int l15 = lane & 15, kg = lane >> 4;
    // XCD-aware swizzle (512 % 8 == 0)
    const int sid = (blockIdx.x & 7) * 64 + (blockIdx.x >> 3);
    const int qt = sid & 31;
    const int b = (sid >> 5) & 3;
    const int sp = sid >> 7;             // key split 0..3
    const int kvoff = sp * KEYS_PER;
    const size_t kvbase = (size_t)b * NN * CI;
    const size_t vbase = (size_t)b * CI * NN;

    // Q as B-fragments: lane holds Q rows (l15, l15+16), d-slice kg*8+j at step kk
    f16x8 qf[2][8];
    {
        const u16* qp0 = Qg + ((size_t)b * NN + qt * 128 + wv * 32 + l15) * CI + kg * 8;
        #pragma unroll
        for (int qs = 0; qs < 2; qs++)
            #pragma unroll
            for (int kk = 0; kk < 8; kk++)
                qf[qs][kk] = *(const f16x8*)(qp0 + (size_t)qs * 16 * CI + kk * 32);
    }

    // acc: O[q][d], col d = dt*16+l15, row q = qs*16 + kg*4 + r
    f32x4 acc[16][2];
    #pragma unroll
    for (int i = 0; i < 16; i++)
        #pragma unroll
        for (int qs = 0; qs < 2; qs++) acc[i][qs] = (f32x4){0.f, 0.f, 0.f, 0.f};
    float mrow[2] = {-1e30f, -1e30f}, lrow[2] = {0.f, 0.f};

    // ---- hoisted staging geometry ----
    const int chunk = tid & 31, rb = tid >> 5;       // K staging
    const u16* ksrc[4];
    int kdst[4];
    #pragma unroll
    for (int i = 0; i < 4; i++) {
        int row = i * 8 + rb;
        int sc = chunk ^ (row & 7);
        ksrc[i] = Kg + kvbase + (size_t)(kvoff + KVB + row) * CI + sc * 8;  // tile 1
        kdst[i] = row * 256 + chunk * 8;
    }
    const int vc = tid & 3, vdb = tid >> 2;          // V staging
    const u16* vsrc[4];
    int vdst[4];
    #pragma unroll
    for (int i = 0; i < 4; i++) {
        int d = i * 64 + vdb;
        int sc = vc ^ ((d >> 1) & 3);
        vsrc[i] = Vtg + vbase + (size_t)d * NN + kvoff + KVB + sc * 8;     // tile 1
        vdst[i] = d * KVB + vc * 8;
    }

    // prologue: stage tile 0 into buffer 0
    #pragma unroll
    for (int i = 0; i < 4; i++) {
        int row = i * 8 + rb;
        int sc = chunk ^ (row & 7);
        gload16(Kg + kvbase + (size_t)(kvoff + row) * CI + sc * 8, smem + kdst[i]);
    }
    #pragma unroll
    for (int i = 0; i < 4; i++) {
        int d = i * 64 + vdb;
        int sc = vc ^ ((d >> 1) & 3);
        gload16(Vtg + vbase + (size_t)d * NN + kvoff + sc * 8, smem + 16384 + vdst[i]);
    }
    __syncthreads();

    for (int it = 0; it < NTILE; ++it) {
        const int cur = (it & 1) * 8192;
        const u16* Ks = smem + cur;
        const u16* Vt = smem + 16384 + cur;
        if (it + 1 < NTILE) {
            const int nxt = cur ^ 8192;
            #pragma unroll
            for (int i = 0; i < 4; i++) {
                gload16(ksrc[i], smem + nxt + kdst[i]);
                ksrc[i] += KVB * CI;
            }
            #pragma unroll
            for (int i = 0; i < 4; i++) {
                gload16(vsrc[i], smem + 16384 + nxt + vdst[i]);
                vsrc[i] += KVB;
            }
        }

        // ---- S^T = K Q^T : lane holds S[key = nt*16+kg*4+r][q = l15+16qs]
        f32x4 s[2][2];
        #pragma unroll
        for (int qs = 0; qs < 2; qs++)
            #pragma unroll
            for (int nt = 0; nt < 2; nt++) s[qs][nt] = (f32x4){0.f, 0.f, 0.f, 0.f};
        __builtin_amdgcn_s_setprio(1);
        #pragma unroll
        for (int kk = 0; kk < 8; kk++) {
            #pragma unroll
            for (int nt = 0; nt < 2; nt++) {
                int krow = nt * 16 + l15;
                f16x8 kf = *(const f16x8*)&Ks[krow * 256 + (((kk * 4 + kg) ^ (krow & 7)) << 3)];
                s[0][nt] = mfma16(kf, qf[0][kk], s[0][nt]);
                s[1][nt] = mfma16(kf, qf[1][kk], s[1][nt]);
            }
        }
        __builtin_amdgcn_s_setprio(0);

        // ---- softmax, lane-local rows (q = l15+16qs); cross-kg reduce via permlane swaps
        float mx[2];
        #pragma unroll
        for (int qs = 0; qs < 2; qs++) {
            float m8 = fmaxf(fmaxf(fmaxf(s[qs][0][0], s[qs][0][1]), fmaxf(s[qs][0][2], s[qs][0][3])),
                             fmaxf(fmaxf(s[qs][1][0], s[qs][1][1]), fmaxf(s[qs][1][2], s[qs][1][3])));
            mx[qs] = redmax4(m8);
        }
        float need = fmaxf(mx[0] - mrow[0], mx[1] - mrow[1]);
        if (!__all(need <= 8.f)) {   // defer-max: rescale only when needed
            float sclv[2];
            #pragma unroll
            for (int qs = 0; qs < 2; qs++) {
                float mnew = fmaxf(mrow[qs], mx[qs]);
                sclv[qs] = __expf(mrow[qs] - mnew);
                lrow[qs] *= sclv[qs];
                mrow[qs] = mnew;
            }
            #pragma unroll
            for (int qs = 0; qs < 2; qs++)
                #pragma unroll
                for (int r = 0; r < 4; r++) {
                    float sr = __shfl(sclv[qs], (lane & 48) | (kg * 4 + r), 64);
                    #pragma unroll
                    for (int dt = 0; dt < 16; dt++) acc[dt][qs][r] *= sr;
                }
        }
        // exp + row-sum + pack P to fp16 A-fragment (keys at mfma-k = kg*8 + nt*4 + r)
        f16x8 pa[2];
        #pragma unroll
        for (int qs = 0; qs < 2; qs++) {
            float rs = 0.f;
            #pragma unroll
            for (int nt = 0; nt < 2; nt++)
                #pragma unroll
                for (int r = 0; r < 4; r++) {
                    float p = __expf(s[qs][nt][r] - mrow[qs]);
                    rs += p;
                    pa[qs][nt * 4 + r] = (_Float16)p;
                }
            lrow[qs] += redsum4(rs);
        }

        // ---- PV: O[q][d] += P(32q x 32k) * V(32k x 256d)
        __builtin_amdgcn_s_setprio(1);
        #pragma unroll
        for (int dt = 0; dt < 16; dt++) {
            int d = dt * 16 + l15;
            f16x8 vf = *(const f16x8*)&Vt[d * KVB + ((kg ^ ((l15 >> 1) & 3)) << 3)];
            acc[dt][0] = mfma16(pa[0], vf, acc[dt][0]);
            acc[dt][1] = mfma16(pa[1], vf, acc[dt][1]);
        }
        __builtin_amdgcn_s_setprio(0);

        __syncthreads();  // waves done with cur buffers; prefetch drained
    }

    // ---- write normalized partial O (fp16) + m/l
    const int row0 = b * NN + qt * 128 + wv * 32;
    u16* pod = (sp < 2) ? (po01 + (size_t)sp * RR * CI)
                        : (po23 + (size_t)(sp - 2) * RR * CI);
    #pragma unroll
    for (int qs = 0; qs < 2; qs++)
        #pragma unroll
        for (int r = 0; r < 4; r++) {
            float li = __shfl(lrow[qs], (lane & 48) | (kg * 4 + r), 64);
            float inv = 1.f / li;
            int row = row0 + qs * 16 + kg * 4 + r;
            #pragma unroll
            for (int dt = 0; dt < 16; dt++)
                pod[(size_t)row * CI + dt * 16 + l15] = f2h(acc[dt][qs][r] * inv);
        }
    if (kg == 0) {
        #pragma unroll
        for (int qs = 0; qs < 2; qs++) {
            int row = row0 + qs * 16 + l15;
            ml[row * 8 + sp * 2] = mrow[qs];
            ml[row * 8 + sp * 2 + 1] = lrow[qs];
        }
    }
}

// ============ combine the four KV-splits (4B/thread) ============
__global__ void attn_combine(const u16* __restrict__ po01, const u16* __restrict__ po23,
                             const float* __restrict__ ml, u16* __restrict__ yb) {
    const int gid = blockIdx.x * 256 + threadIdx.x;  // RR*CI/4 threads
    const int row = gid >> 6;
    const int d0 = (gid & 63) * 4;
    f32x4 ml0 = ((const f32x4*)ml)[row * 2];
    f32x4 ml1 = ((const f32x4*)ml)[row * 2 + 1];
    float m = fmaxf(fmaxf(ml0[0], ml0[2]), fmaxf(ml1[0], ml1[2]));
    float c0 = __expf(ml0[0] - m) * ml0[1];
    float c1 = __expf(ml0[2] - m) * ml0[3];
    float c2 = __expf(ml1[0] - m) * ml1[1];
    float c3 = __expf(ml1[2] - m) * ml1[3];
    float inv = 1.f / (c0 + c1 + c2 + c3);
    const size_t off = (size_t)row * CI + d0;
    const size_t spstride = (size_t)RR * CI;
    u16x4 p0 = *(const u16x4*)(po01 + off);
    u16x4 p1 = *(const u16x4*)(po01 + spstride + off);
    u16x4 p2 = *(const u16x4*)(po23 + off);
    u16x4 p3 = *(const u16x4*)(po23 + spstride + off);
    u16x4 o;
    #pragma unroll
    for (int e = 0; e < 4; e++)
        o[e] = f2h((c0 * h2f(p0[e]) + c1 * h2f(p1[e]) +
                    c2 * h2f(p2[e]) + c3 * h2f(p3[e])) * inv);
    *(u16x4*)(yb + off) = o;
}

// ============ launcher ============
extern "C" void kernel_launch(void* const* d_in, const int* in_sizes, int n_in,
                              void* d_out, int out_size, void* d_ws, size_t ws_size,
                              hipStream_t stream) {
    (void)in_sizes; (void)n_in; (void)out_size; (void)ws_size;
    const float* x     = (const float*)d_in[0];
    const float* gamma = (const float*)d_in[1];
    const float* beta  = (const float*)d_in[2];
    const float* thw   = (const float*)d_in[3];
    const float* thb   = (const float*)d_in[4];
    const float* phw   = (const float*)d_in[5];
    const float* phb   = (const float*)d_in[6];
    const float* gw    = (const float*)d_in[7];
    const float* gb    = (const float*)d_in[8];
    const float* ww    = (const float*)d_in[9];
    const float* wb    = (const float*)d_in[10];

    char* ws = (char*)d_ws;
    u16* po01  = (u16*)(ws + OFF_FEAT);   // attn partial O splits 0,1 (16MB)
    u16* qb    = (u16*)(ws + OFF_Q);
    u16* kb    = (u16*)(ws + OFF_K);
    u16* vtb   = (u16*)(ws + OFF_V);
    u16* yb    = (u16*)(ws + OFF_Y);      // yb (8MB); bn partials (512KB) EARLY (disjoint in time)
    u16* wqkv  = (u16*)(ws + OFF_WQKV);
    u16* wo    = (u16*)(ws + OFF_WO);
    float* bqkv = (float*)(ws + OFF_BQKV);
    float* bnpart = (float*)(ws + OFF_Y); // consumed by prep before yb written
    float* mlp  = (float*)(ws + OFF_PART); // attn m/l (512KB)
    float* ss   = (float*)(ws + OFF_SS);
    float* out  = (float*)d_out;
    u16* po23  = (u16*)d_out;             // scratch: first 16MB of d_out = splits 2,3

    (void)hipFuncSetAttribute((const void*)attn_kernel,
                              hipFuncAttributeMaxDynamicSharedMemorySize, ATTN_LDS);

    bn_partial<<<128, 512, 0, stream>>>(x, bnpart);
    prep_kernel<<<1025, 512, 0, stream>>>(bnpart, gamma, beta, ss,
                                          thw, phw, gw, thb, phb, gb, ww, wqkv, wo, bqkv);
    gemm_bt<0><<<dim3(128, 3), 512, 0, stream>>>(nullptr, x, ss, wqkv, 512, bqkv, nullptr,
                                                 qb, kb, vtb, nullptr);
    attn_kernel<<<512, 256, ATTN_LDS, stream>>>(qb, kb, vtb, po01, po23, mlp);
    attn_combine<<<RR * CI / 4 / 256, 256, 0, stream>>>(po01, po23, mlp, yb);
    gemm_bt<1><<<dim3(128, 2), 512, 0, stream>>>(yb, nullptr, nullptr, wo, 256, wb, x,
                                                 nullptr, nullptr, nullptr, out);
}

// Round 17
// 159.887 us; speedup vs baseline: 1.0255x; 1.0255x over previous
//
#include <hip/hip_runtime.h>

typedef unsigned short u16;
typedef __attribute__((ext_vector_type(4))) float f32x4;
typedef __attribute__((ext_vector_type(8))) _Float16 f16x8;
typedef __attribute__((ext_vector_type(8))) unsigned short u16x8;
typedef __attribute__((ext_vector_type(4))) unsigned short u16x4;

#define DEV __device__ __forceinline__

// ---------- helpers ----------
DEV u16 f2h(float f) {
    _Float16 h = (_Float16)f;
    u16 r;
    __builtin_memcpy(&r, &h, 2);
    return r;
}
DEV float h2f(u16 u) {
    _Float16 h;
    __builtin_memcpy(&h, &u, 2);
    return (float)h;
}

DEV f32x4 mfma16(f16x8 a, f16x8 b, f32x4 c) {
    return __builtin_amdgcn_mfma_f32_16x16x32_f16(a, b, c, 0, 0, 0);
}

DEV void gload16(const void* g, void* l) {
    __builtin_amdgcn_global_load_lds(
        (const __attribute__((address_space(1))) void*)g,
        (__attribute__((address_space(3))) void*)l, 16, 0, 0);
}

// ---- cross-lane reduce over lanes {l ^ 16, l ^ 32} (same l15, kg=0..3) ----
// permlane{16,32}_swap are pure-VALU (no LDS pipe) vs ds_bpermute (~30-60 cyc + LDS pipe).
#if __has_builtin(__builtin_amdgcn_permlane16_swap) && __has_builtin(__builtin_amdgcn_permlane32_swap)
DEV float redmax4(float x) {
    unsigned u = __float_as_uint(x);
    auto a = __builtin_amdgcn_permlane16_swap(u, u, false, false);
    x = fmaxf(__uint_as_float(a[0]), __uint_as_float(a[1]));
    u = __float_as_uint(x);
    auto b = __builtin_amdgcn_permlane32_swap(u, u, false, false);
    return fmaxf(__uint_as_float(b[0]), __uint_as_float(b[1]));
}
DEV float redsum4(float x) {
    unsigned u = __float_as_uint(x);
    auto a = __builtin_amdgcn_permlane16_swap(u, u, false, false);
    x = __uint_as_float(a[0]) + __uint_as_float(a[1]);
    u = __float_as_uint(x);
    auto b = __builtin_amdgcn_permlane32_swap(u, u, false, false);
    return __uint_as_float(b[0]) + __uint_as_float(b[1]);
}
#else
DEV float redmax4(float x) {
    x = fmaxf(x, __shfl_xor(x, 16));
    return fmaxf(x, __shfl_xor(x, 32));
}
DEV float redsum4(float x) {
    x += __shfl_xor(x, 16);
    return x + __shfl_xor(x, 32);
}
#endif

// ---------- problem constants ----------
#define BB 4
#define NN 4096
#define CC 512
#define CI 256
#define RR (BB * NN)  // 16384

// ---------- workspace layout (bytes) ----------
#define OFF_FEAT 0u                     // 16 MB: attn partial O splits 0,1
#define OFF_Q    16777216u
#define OFF_K    25165824u
#define OFF_V    33554432u              // V^T layout [b][d][key], keys sigma-permuted per 32
#define OFF_Y    41943040u              // 8MB: bn partials (512KB) early; yb (8MB) later
#define OFF_WQKV 50331648u
#define OFF_WO   51118080u
#define OFF_BQKV 51380224u
#define OFF_PART 51383296u              // 512KB: attn m/l
#define OFF_SS   51907584u

// ============ BN stats ============
__global__ void bn_partial(const float* __restrict__ x, float* __restrict__ part) {
    const int c = threadIdx.x;
    const int blk = blockIdx.x;           // 128 blocks x 128 rows
    const float* xp = x + (size_t)blk * 128 * CC + c;
    float s = 0.f, q = 0.f;
    for (int r = 0; r < 128; r++) {
        float v = xp[(size_t)r * CC];
        s += v; q += v * v;
    }
    part[blk * 1024 + c] = s;
    part[blk * 1024 + 512 + c] = q;
}

// ============ merged: bn_final (block 1024) + weight cvt (blocks 0..1023) ============
__global__ void prep_kernel(const float* __restrict__ part,
                            const float* __restrict__ gamma, const float* __restrict__ beta,
                            float* __restrict__ ss,
                            const float* __restrict__ thw, const float* __restrict__ phw,
                            const float* __restrict__ gw,
                            const float* __restrict__ thb, const float* __restrict__ phb,
                            const float* __restrict__ gb,
                            const float* __restrict__ ww,
                            u16* __restrict__ wqkv, u16* __restrict__ wo,
                            float* __restrict__ bqkv) {
    if (blockIdx.x == 1024) {
        const int c = threadIdx.x;  // 512 threads
        float s = 0.f, q = 0.f;
        for (int i = 0; i < 128; i++) {
            s += part[i * 1024 + c];
            q += part[i * 1024 + 512 + c];
        }
        float m = s * (1.0f / (float)RR);
        float var = q * (1.0f / (float)RR) - m * m;
        float istd = rsqrtf(var + 1e-5f);
        float g = gamma[c] * istd;
        ss[c] = g;
        ss[512 + c] = beta[c] - m * g;
        return;
    }
    const int idx = blockIdx.x * 512 + threadIdx.x;  // 0..524287
    if (idx < 768 * 512) {
        int row = idx >> 9, col = idx & 511;
        float v = (row < 256) ? thw[row * 512 + col]
                : (row < 512) ? phw[(row - 256) * 512 + col]
                              : gw[(row - 512) * 512 + col];
        wqkv[idx] = f2h(v);
    } else {
        int j = idx - 768 * 512;  // < 512*256
        wo[j] = f2h(ww[j]);
    }
    if (idx < 768) {
        bqkv[idx] = (idx < 256) ? thb[idx] : (idx < 512) ? phb[idx - 256] : gb[idx - 512];
    }
}

// ============ GEMM, 128x128 tile ============
// MODE 0: A = BN+ReLU(x) on the fly; grid (128,6); Q,K row-major; V^T sigma-permuted
// MODE 1: A = yb fp16 (gload_lds); grid (128,4); out = x + A*B^T + bias -> fp32
template <int MODE>
__global__ __launch_bounds__(256) void gemm_bt(
    const u16* __restrict__ A, const float* __restrict__ X, const float* __restrict__ ss,
    const u16* __restrict__ Bm, int K,
    const float* __restrict__ bias, const float* __restrict__ xres,
    u16* __restrict__ oq, u16* __restrict__ okk, u16* __restrict__ ov,
    float* __restrict__ of) {
    __shared__ u16 As[128 * 32];
    __shared__ u16 Bs[128 * 32];
    const int tid = threadIdx.x;
    const int lane = tid & 63;
    const int l15 = lane & 15, kg = lane >> 4;
    const int wv = tid >> 6;
    const int wm = wv >> 1, wn = wv & 1;
    const int m0 = blockIdx.x * 128, n0 = blockIdx.y * 128;

    f32x4 acc[4][4];
    #pragma unroll
    for (int i = 0; i < 4; i++)
        #pragma unroll
        for (int j = 0; j < 4; j++) acc[i][j] = (f32x4){0.f, 0.f, 0.f, 0.f};

    const int rowA = tid >> 2, colA = (tid & 3) * 8;
    for (int k0 = 0; k0 < K; k0 += 32) {
        if constexpr (MODE == 0) {
            // fused BN+ReLU A-staging from x (fp32)
            const float* xa = X + (size_t)(m0 + rowA) * CC + k0 + colA;
            f32x4 xv0 = *(const f32x4*)(xa);
            f32x4 xv1 = *(const f32x4*)(xa + 4);
            f32x4 xv2 = *(const f32x4*)(xa + (size_t)64 * CC);
            f32x4 xv3 = *(const f32x4*)(xa + (size_t)64 * CC + 4);
            f32x4 sc0 = *(const f32x4*)(ss + k0 + colA);
            f32x4 sc1 = *(const f32x4*)(ss + k0 + colA + 4);
            f32x4 sh0 = *(const f32x4*)(ss + 512 + k0 + colA);
            f32x4 sh1 = *(const f32x4*)(ss + 512 + k0 + colA + 4);
            u16x8 a0, a1;
            #pragma unroll
            for (int e = 0; e < 4; e++) {
                a0[e]     = f2h(fmaxf(xv0[e] * sc0[e] + sh0[e], 0.f));
                a0[4 + e] = f2h(fmaxf(xv1[e] * sc1[e] + sh1[e], 0.f));
                a1[e]     = f2h(fmaxf(xv2[e] * sc0[e] + sh0[e], 0.f));
                a1[4 + e] = f2h(fmaxf(xv3[e] * sc1[e] + sh1[e], 0.f));
            }
            *(u16x8*)&As[tid * 8] = a0;
            *(u16x8*)&As[2048 + tid * 8] = a1;
        } else {
            gload16(A + (size_t)(m0 + rowA) * K + k0 + colA, &As[tid * 8]);
            gload16(A + (size_t)(m0 + 64 + rowA) * K + k0 + colA, &As[2048 + tid * 8]);
        }
        gload16(Bm + (size_t)(n0 + rowA) * K + k0 + colA, &Bs[tid * 8]);
        gload16(Bm + (size_t)(n0 + 64 + rowA) * K + k0 + colA, &Bs[2048 + tid * 8]);
        __syncthreads();
        f16x8 af[4], bfr[4];
        #pragma unroll
        for (int i = 0; i < 4; i++)
            af[i] = *(const f16x8*)&As[(wm * 64 + i * 16 + l15) * 32 + kg * 8];
        #pragma unroll
        for (int i = 0; i < 4; i++)
            bfr[i] = *(const f16x8*)&Bs[(wn * 64 + i * 16 + l15) * 32 + kg * 8];
        #pragma unroll
        for (int mi = 0; mi < 4; mi++)
            #pragma unroll
            for (int ni = 0; ni < 4; ni++)
                acc[mi][ni] = mfma16(af[mi], bfr[ni], acc[mi][ni]);
        __syncthreads();
    }

    #pragma unroll
    for (int mi = 0; mi < 4; mi++) {
        #pragma unroll
        for (int ni = 0; ni < 4; ni++) {
            #pragma unroll
            for (int r = 0; r < 4; r++) {
                int row = m0 + wm * 64 + mi * 16 + kg * 4 + r;
                int col = n0 + wn * 64 + ni * 16 + l15;
                float v = acc[mi][ni][r];
                if constexpr (MODE == 0) {
                    v += bias[col];
                    u16 hv = f2h(v);
                    if (col < 256) {
                        oq[(size_t)row * CI + col] = hv;
                    } else if (col < 512) {
                        okk[(size_t)row * CI + (col - 256)] = hv;
                    } else {
                        int d = col - 512;
                        int bi = row >> 12, key = row & (NN - 1);
                        int k5 = key & 31;
                        int skey = (key & ~31) |
                                   ((((k5 >> 2) & 3) << 3) | (k5 & 3) | (((k5 >> 4) & 1) << 2));
                        ov[((size_t)bi * CI + d) * NN + skey] = hv;  // V^T, sigma-permuted
                    }
                } else {
                    size_t o = (size_t)row * 512 + col;
                    of[o] = xres[o] + v + bias[col];
                }
            }
        }
    }
}

// ============ flash attention, swapped-QK^T, 32 q-rows/wave, split-KV x4 ============
// grid 512 = 4 batches x 32 q-tiles(128 rows) x 4 key-splits; block 256 = 4 waves x 32 q-rows
// LDS: Ks 2x[32][256] swz (32KB dbuf) | Vt 2x[256][32] swz (32KB dbuf) = 65536 B
#define KVB 32
#define NSPLIT 4
#define KEYS_PER (NN / NSPLIT)          // 1024
#define NTILE (KEYS_PER / KVB)          // 32
#define ATTN_LDS 65536

__global__ __launch_bounds__(256, 2) void attn_kernel(
    const u16* __restrict__ Qg, const u16* __restrict__ Kg,
    const u16* __restrict__ Vtg, u16* __restrict__ po01, u16* __restrict__ po23,
    float* __restrict__ ml) {
    extern __shared__ u16 smem[];

    const int tid = threadIdx.x, lane = tid & 63, wv = tid >> 6;
    const int l15 = lane & 15, kg = lane >> 4;
    // XCD-aware swizzle (512 % 8 == 0)
    const int sid = (blockIdx.x & 7) * 64 + (blockIdx.x >> 3);
    const int qt = sid & 31;
    const int b = (sid >> 5) & 3;
    const int sp = sid >> 7;             // key split 0..3
    const int kvoff = sp * KEYS_PER;
    const size_t kvbase = (size_t)b * NN * CI;
    const size_t vbase = (size_t)b * CI * NN;

    // Q as B-fragments: lane holds Q rows (l15, l15+16), d-slice kg*8+j at step kk
    f16x8 qf[2][8];
    {
        const u16* qp0 = Qg + ((size_t)b * NN + qt * 128 + wv * 32 + l15) * CI + kg * 8;
        #pragma unroll
        for (int qs = 0; qs < 2; qs++)
            #pragma unroll
            for (int kk = 0; kk < 8; kk++)
                qf[qs][kk] = *(const f16x8*)(qp0 + (size_t)qs * 16 * CI + kk * 32);
    }

    // acc: O[q][d], col d = dt*16+l15, row q = qs*16 + kg*4 + r
    f32x4 acc[16][2];
    #pragma unroll
    for (int i = 0; i < 16; i++)
        #pragma unroll
        for (int qs = 0; qs < 2; qs++) acc[i][qs] = (f32x4){0.f, 0.f, 0.f, 0.f};
    float mrow[2] = {-1e30f, -1e30f}, lrow[2] = {0.f, 0.f};

    // ---- hoisted staging geometry ----
    const int chunk = tid & 31, rb = tid >> 5;       // K staging
    const u16* ksrc[4];
    int kdst[4];
    #pragma unroll
    for (int i = 0; i < 4; i++) {
        int row = i * 8 + rb;
        int sc = chunk ^ (row & 7);
        ksrc[i] = Kg + kvbase + (size_t)(kvoff + KVB + row) * CI + sc * 8;  // tile 1
        kdst[i] = row * 256 + chunk * 8;
    }
    const int vc = tid & 3, vdb = tid >> 2;          // V staging
    const u16* vsrc[4];
    int vdst[4];
    #pragma unroll
    for (int i = 0; i < 4; i++) {
        int d = i * 64 + vdb;
        int sc = vc ^ ((d >> 1) & 3);
        vsrc[i] = Vtg + vbase + (size_t)d * NN + kvoff + KVB + sc * 8;     // tile 1
        vdst[i] = d * KVB + vc * 8;
    }

    // prologue: stage tile 0 into buffer 0
    #pragma unroll
    for (int i = 0; i < 4; i++) {
        int row = i * 8 + rb;
        int sc = chunk ^ (row & 7);
        gload16(Kg + kvbase + (size_t)(kvoff + row) * CI + sc * 8, smem + kdst[i]);
    }
    #pragma unroll
    for (int i = 0; i < 4; i++) {
        int d = i * 64 + vdb;
        int sc = vc ^ ((d >> 1) & 3);
        gload16(Vtg + vbase + (size_t)d * NN + kvoff + sc * 8, smem + 16384 + vdst[i]);
    }
    __syncthreads();

    for (int it = 0; it < NTILE; ++it) {
        const int cur = (it & 1) * 8192;
        const u16* Ks = smem + cur;
        const u16* Vt = smem + 16384 + cur;
        if (it + 1 < NTILE) {
            const int nxt = cur ^ 8192;
            #pragma unroll
            for (int i = 0; i < 4; i++) {
                gload16(ksrc[i], smem + nxt + kdst[i]);
                ksrc[i] += KVB * CI;
            }
            #pragma unroll
            for (int i = 0; i < 4; i++) {
                gload16(vsrc[i], smem + 16384 + nxt + vdst[i]);
                vsrc[i] += KVB;
            }
        }

        // ---- S^T = K Q^T : lane holds S[key = nt*16+kg*4+r][q = l15+16qs]
        f32x4 s[2][2];
        #pragma unroll
        for (int qs = 0; qs < 2; qs++)
            #pragma unroll
            for (int nt = 0; nt < 2; nt++) s[qs][nt] = (f32x4){0.f, 0.f, 0.f, 0.f};
        __builtin_amdgcn_s_setprio(1);
        #pragma unroll
        for (int kk = 0; kk < 8; kk++) {
            #pragma unroll
            for (int nt = 0; nt < 2; nt++) {
                int krow = nt * 16 + l15;
                f16x8 kf = *(const f16x8*)&Ks[krow * 256 + (((kk * 4 + kg) ^ (krow & 7)) << 3)];
                s[0][nt] = mfma16(kf, qf[0][kk], s[0][nt]);
                s[1][nt] = mfma16(kf, qf[1][kk], s[1][nt]);
            }
        }
        __builtin_amdgcn_s_setprio(0);

        // ---- softmax, lane-local rows (q = l15+16qs); cross-kg reduce via permlane swaps
        float mx[2];
        #pragma unroll
        for (int qs = 0; qs < 2; qs++) {
            float m8 = fmaxf(fmaxf(fmaxf(s[qs][0][0], s[qs][0][1]), fmaxf(s[qs][0][2], s[qs][0][3])),
                             fmaxf(fmaxf(s[qs][1][0], s[qs][1][1]), fmaxf(s[qs][1][2], s[qs][1][3])));
            mx[qs] = redmax4(m8);
        }
        float need = fmaxf(mx[0] - mrow[0], mx[1] - mrow[1]);
        if (!__all(need <= 8.f)) {   // defer-max: rescale only when needed
            float sclv[2];
            #pragma unroll
            for (int qs = 0; qs < 2; qs++) {
                float mnew = fmaxf(mrow[qs], mx[qs]);
                sclv[qs] = __expf(mrow[qs] - mnew);
                lrow[qs] *= sclv[qs];
                mrow[qs] = mnew;
            }
            #pragma unroll
            for (int qs = 0; qs < 2; qs++)
                #pragma unroll
                for (int r = 0; r < 4; r++) {
                    float sr = __shfl(sclv[qs], (lane & 48) | (kg * 4 + r), 64);
                    #pragma unroll
                    for (int dt = 0; dt < 16; dt++) acc[dt][qs][r] *= sr;
                }
        }
        // exp + row-sum + pack P to fp16 A-fragment (keys at mfma-k = kg*8 + nt*4 + r)
        f16x8 pa[2];
        #pragma unroll
        for (int qs = 0; qs < 2; qs++) {
            float rs = 0.f;
            #pragma unroll
            for (int nt = 0; nt < 2; nt++)
                #pragma unroll
                for (int r = 0; r < 4; r++) {
                    float p = __expf(s[qs][nt][r] - mrow[qs]);
                    rs += p;
                    pa[qs][nt * 4 + r] = (_Float16)p;
                }
            lrow[qs] += redsum4(rs);
        }

        // ---- PV: O[q][d] += P(32q x 32k) * V(32k x 256d)
        __builtin_amdgcn_s_setprio(1);
        #pragma unroll
        for (int dt = 0; dt < 16; dt++) {
            int d = dt * 16 + l15;
            f16x8 vf = *(const f16x8*)&Vt[d * KVB + ((kg ^ ((l15 >> 1) & 3)) << 3)];
            acc[dt][0] = mfma16(pa[0], vf, acc[dt][0]);
            acc[dt][1] = mfma16(pa[1], vf, acc[dt][1]);
        }
        __builtin_amdgcn_s_setprio(0);

        __syncthreads();  // waves done with cur buffers; prefetch drained
    }

    // ---- write normalized partial O (fp16) + m/l
    const int row0 = b * NN + qt * 128 + wv * 32;
    u16* pod = (sp < 2) ? (po01 + (size_t)sp * RR * CI)
                        : (po23 + (size_t)(sp - 2) * RR * CI);
    #pragma unroll
    for (int qs = 0; qs < 2; qs++)
        #pragma unroll
        for (int r = 0; r < 4; r++) {
            float li = __shfl(lrow[qs], (lane & 48) | (kg * 4 + r), 64);
            float inv = 1.f / li;
            int row = row0 + qs * 16 + kg * 4 + r;
            #pragma unroll
            for (int dt = 0; dt < 16; dt++)
                pod[(size_t)row * CI + dt * 16 + l15] = f2h(acc[dt][qs][r] * inv);
        }
    if (kg == 0) {
        #pragma unroll
        for (int qs = 0; qs < 2; qs++) {
            int row = row0 + qs * 16 + l15;
            ml[row * 8 + sp * 2] = mrow[qs];
            ml[row * 8 + sp * 2 + 1] = lrow[qs];
        }
    }
}

// ============ combine the four KV-splits (4B/thread) ============
__global__ void attn_combine(const u16* __restrict__ po01, const u16* __restrict__ po23,
                             const float* __restrict__ ml, u16* __restrict__ yb) {
    const int gid = blockIdx.x * 256 + threadIdx.x;  // RR*CI/4 threads
    const int row = gid >> 6;
    const int d0 = (gid & 63) * 4;
    f32x4 ml0 = ((const f32x4*)ml)[row * 2];
    f32x4 ml1 = ((const f32x4*)ml)[row * 2 + 1];
    float m = fmaxf(fmaxf(ml0[0], ml0[2]), fmaxf(ml1[0], ml1[2]));
    float c0 = __expf(ml0[0] - m) * ml0[1];
    float c1 = __expf(ml0[2] - m) * ml0[3];
    float c2 = __expf(ml1[0] - m) * ml1[1];
    float c3 = __expf(ml1[2] - m) * ml1[3];
    float inv = 1.f / (c0 + c1 + c2 + c3);
    const size_t off = (size_t)row * CI + d0;
    const size_t spstride = (size_t)RR * CI;
    u16x4 p0 = *(const u16x4*)(po01 + off);
    u16x4 p1 = *(const u16x4*)(po01 + spstride + off);
    u16x4 p2 = *(const u16x4*)(po23 + off);
    u16x4 p3 = *(const u16x4*)(po23 + spstride + off);
    u16x4 o;
    #pragma unroll
    for (int e = 0; e < 4; e++)
        o[e] = f2h((c0 * h2f(p0[e]) + c1 * h2f(p1[e]) +
                    c2 * h2f(p2[e]) + c3 * h2f(p3[e])) * inv);
    *(u16x4*)(yb + off) = o;
}

// ============ launcher ============
extern "C" void kernel_launch(void* const* d_in, const int* in_sizes, int n_in,
                              void* d_out, int out_size, void* d_ws, size_t ws_size,
                              hipStream_t stream) {
    (void)in_sizes; (void)n_in; (void)out_size; (void)ws_size;
    const float* x     = (const float*)d_in[0];
    const float* gamma = (const float*)d_in[1];
    const float* beta  = (const float*)d_in[2];
    const float* thw   = (const float*)d_in[3];
    const float* thb   = (const float*)d_in[4];
    const float* phw   = (const float*)d_in[5];
    const float* phb   = (const float*)d_in[6];
    const float* gw    = (const float*)d_in[7];
    const float* gb    = (const float*)d_in[8];
    const float* ww    = (const float*)d_in[9];
    const float* wb    = (const float*)d_in[10];

    char* ws = (char*)d_ws;
    u16* po01  = (u16*)(ws + OFF_FEAT);   // attn partial O splits 0,1 (16MB)
    u16* qb    = (u16*)(ws + OFF_Q);
    u16* kb    = (u16*)(ws + OFF_K);
    u16* vtb   = (u16*)(ws + OFF_V);
    u16* yb    = (u16*)(ws + OFF_Y);      // yb (8MB); bn partials (512KB) EARLY (disjoint in time)
    u16* wqkv  = (u16*)(ws + OFF_WQKV);
    u16* wo    = (u16*)(ws + OFF_WO);
    float* bqkv = (float*)(ws + OFF_BQKV);
    float* bnpart = (float*)(ws + OFF_Y); // consumed by prep before yb written
    float* mlp  = (float*)(ws + OFF_PART); // attn m/l (512KB)
    float* ss   = (float*)(ws + OFF_SS);
    float* out  = (float*)d_out;
    u16* po23  = (u16*)d_out;             // scratch: first 16MB of d_out = splits 2,3

    (void)hipFuncSetAttribute((const void*)attn_kernel,
                              hipFuncAttributeMaxDynamicSharedMemorySize, ATTN_LDS);

    bn_partial<<<128, 512, 0, stream>>>(x, bnpart);
    prep_kernel<<<1025, 512, 0, stream>>>(bnpart, gamma, beta, ss,
                                          thw, phw, gw, thb, phb, gb, ww, wqkv, wo, bqkv);
    gemm_bt<0><<<dim3(128, 6), 256, 0, stream>>>(nullptr, x, ss, wqkv, 512, bqkv, nullptr,
                                                 qb, kb, vtb, nullptr);
    attn_kernel<<<512, 256, ATTN_LDS, stream>>>(qb, kb, vtb, po01, po23, mlp);
    attn_combine<<<RR * CI / 4 / 256, 256, 0, stream>>>(po01, po23, mlp, yb);
    gemm_bt<1><<<dim3(128, 4), 256, 0, stream>>>(yb, nullptr, nullptr, wo, 256, wb, x,
                                                 nullptr, nullptr, nullptr, out);
}